// Round 9
// baseline (87.936 us; speedup 1.0000x reference)
//
#include <hip/hip_runtime.h>

typedef __attribute__((ext_vector_type(8))) short short8;
typedef __attribute__((ext_vector_type(4))) float f32x4;

#define CIN 256
#define OUTC 256
#define HWW 4096
#define IMG_H 64
#define IMG_W 64
#define SROW 264   // offs_mfma LDS row stride (256 + 8 pad)
#define SB __builtin_amdgcn_sched_barrier(0)

__device__ __forceinline__ short f2bf(float f) {
    unsigned u = __float_as_uint(f);
    u += 0x7fffu + ((u >> 16) & 1u);
    return (short)(u >> 16);
}
__device__ __forceinline__ float bf2f(short s) {
    return __uint_as_float(((unsigned)(unsigned short)s) << 16);
}

// ---------------- Fused prep: xpose (0..1023), wprep 16-octile layout
//                  (1024..1311), wprep_off (1312..1347) ----------------
__global__ __launch_bounds__(256) void prep(const float* __restrict__ x,
                                            const float* __restrict__ w_dcn,
                                            const float* __restrict__ w_off,
                                            short* __restrict__ xT,
                                            short* __restrict__ wF,
                                            short* __restrict__ wFo) {
    int bid = blockIdx.x;
    if (bid < 1024) {
        __shared__ float T[64][65];
        int p0 = (bid & 63) * 64;
        int c0 = ((bid >> 6) & 3) * 64;
        int b  = bid >> 8;
        int j = threadIdx.x & 63, i = threadIdx.x >> 6;
        const float* xb = x + ((size_t)b * CIN + c0) * HWW + p0;
#pragma unroll
        for (int k = 0; k < 16; ++k) {
            int row = i * 16 + k;
            T[row][j] = xb[(size_t)row * HWW + j];
        }
        __syncthreads();
        short* xTb = xT + ((size_t)b * HWW + p0) * CIN + c0;
#pragma unroll
        for (int k = 0; k < 16; ++k) {
            int prow = i * 16 + k;
            xTb[(size_t)prow * CIN + j] = f2bf(T[j][prow]);
        }
    } else if (bid < 1312) {
        // wF entry g = ((step*16 + octile)*64 + lane); step = kp*8 + chv;
        // oc = octile*16 + (lane&15), c = chv*32 + (lane>>4)*8 + j.
        int g = (bid - 1024) * 256 + threadIdx.x;   // 73728
        int lane = g & 63;
        int rest = g >> 6;
        int octile = rest & 15;
        int step = rest >> 4;
        int kp = step >> 3, chv = step & 7;
        int oc = octile * 16 + (lane & 15);
        int cbase = chv * 32 + (lane >> 4) * 8;
        short8 v;
#pragma unroll
        for (int j = 0; j < 8; ++j)
            v[j] = f2bf(w_dcn[oc * 2304 + (cbase + j) * 9 + kp]);
        *(short8*)(wF + (size_t)g * 8) = v;
    } else {
        int g = (bid - 1312) * 256 + threadIdx.x;   // 9216
        int lane = g & 63;
        int rest = g >> 6;
        int octile = rest & 1;
        int step = rest >> 1;
        int kp = step >> 3, chv = step & 7;
        int oc = octile * 16 + (lane & 15);
        int cbase = chv * 32 + (lane >> 4) * 8;
        short8 v;
#pragma unroll
        for (int j = 0; j < 8; ++j)
            v[j] = (oc < 27) ? f2bf(w_off[(oc * 256 + cbase + j) * 9 + kp]) : (short)0;
        *(short8*)(wFo + (size_t)g * 8) = v;
    }
}

// ---------------- Offset conv: 16x16 MFMA path (unchanged) ----------------
__global__ __launch_bounds__(256) void offs_mfma(
        const short* __restrict__ xT, const short* __restrict__ wFo,
        float* __restrict__ P) {
    __shared__ short Sm[2][32 * SROW];

    int tid = threadIdx.x;
    int d = blockIdx.x;
    int L = (d & 7) * 64 + (d >> 3);
    int b = L >> 7;
    int ph = L & 127;
    int pbase = ph * 32;
    int prow = ph >> 1;
    int pc0 = (ph & 1) * 32;
    const short* xTb = xT + (size_t)b * HWW * CIN;

    int lane = tid & 63, wave = tid >> 6;
    int fr = lane & 15, fq = lane >> 4;
    int octile = wave & 1, pxt = wave >> 1;

    short8 st[4];

    auto loads = [&](int kp) {
        int yy = prow - 1 + kp / 3;
        int dx = kp % 3 - 1;
#pragma unroll
        for (int it = 0; it < 4; ++it) {
            int item = tid + it * 256;
            int cg8 = item & 31, px = item >> 5;
            int xx = pc0 + px + dx;
            bool ok = (yy >= 0 && yy < IMG_H && xx >= 0 && xx < IMG_W);
            int idx = ok ? ((yy * IMG_W + xx) * CIN + cg8 * 8) : 0;
            short8 v = *(const short8*)&xTb[idx];
            if (!ok) v = (short8){0,0,0,0,0,0,0,0};
            st[it] = v;
        }
    };
    auto writes = [&](int bufi) {
#pragma unroll
        for (int it = 0; it < 4; ++it) {
            int item = tid + it * 256;
            int cg8 = item & 31, px = item >> 5;
            *(short8*)&Sm[bufi][px * SROW + cg8 * 8] = st[it];
        }
    };

    f32x4 acc = (f32x4){0.f, 0.f, 0.f, 0.f};

    loads(0); writes(0);
    __syncthreads();
    for (int kp = 0; kp < 9; ++kp) {
        short8 aF[8];
#pragma unroll
        for (int chv = 0; chv < 8; ++chv)
            aF[chv] = *(const short8*)(wFo +
                    (((size_t)((kp * 8 + chv) * 2 + octile)) * 64 + lane) * 8);
        if (kp < 8) loads(kp + 1);
        const short* SmB = Sm[kp & 1];
#pragma unroll
        for (int chv = 0; chv < 8; ++chv) {
            short8 bF = *(const short8*)&SmB[(pxt * 16 + fr) * SROW + chv * 32 + fq * 8];
            acc = __builtin_amdgcn_mfma_f32_16x16x32_bf16(aF[chv], bF, acc, 0, 0, 0);
        }
        if (kp < 8) writes((kp + 1) & 1);
        __syncthreads();
    }

#pragma unroll
    for (int r = 0; r < 4; ++r) {
        int oc = octile * 16 + fq * 4 + r;
        if (oc < 27)
            P[((size_t)b * 32 + oc) * HWW + pbase + pxt * 16 + fr] = acc[r];
    }
}

// ---------------- Main: K-split siblings. Block = (ks, b, row):
// 64px x 256oc x 128c-half. 512 blocks -> 2/CU. atomicAdd merge. ----------------
__global__ __launch_bounds__(512, 4) void dcn_main(
        const short* __restrict__ xT, const float* __restrict__ b_off,
        const float* __restrict__ P, const short* __restrict__ wF,
        float* __restrict__ out) {
    __shared__ short Sm[2][16 * 64 * 8];    // 2 x 16 KB, XOR layout
    __shared__ float4 preW[576];            // [kp][px]
    __shared__ int4  preI[576];             // [kp][px] elem offsets (idx*CIN)

    int tid = threadIdx.x;
    int d = blockIdx.x;
    int L = (d & 7) * 64 + (d >> 3);        // XCD swizzle: 512 blocks
    int ks = L >> 8;                        // K-half
    int b = (L >> 6) & 3;
    int row = L & 63;
    int pbase = row * 64;
    const short* xTb = xT + (size_t)b * HWW * CIN;

    for (int e = tid; e < 576; e += 512) {
        int px = e & 63, kp = e >> 6;
        int p = pbase + px;
        float oy = P[((size_t)b * 32 + 2 * kp) * HWW + p] + b_off[2 * kp];
        float ox = P[((size_t)b * 32 + 2 * kp + 1) * HWW + p] + b_off[2 * kp + 1];
        float ml = P[((size_t)b * 32 + 18 + kp) * HWW + p] + b_off[18 + kp];
        float m = 1.0f / (1.0f + expf(-ml));
        float ys = (float)(row - 1 + kp / 3) + oy;
        float xs = (float)(px - 1 + kp % 3) + ox;
        float y0f = floorf(ys), x0f = floorf(xs);
        float fy = ys - y0f, fx = xs - x0f;
        int iy0 = (int)y0f, ix0 = (int)x0f;
        int iy1 = iy0 + 1, ix1 = ix0 + 1;
        float vy0 = (iy0 >= 0 && iy0 < IMG_H) ? 1.f : 0.f;
        float vy1 = (iy1 >= 0 && iy1 < IMG_H) ? 1.f : 0.f;
        float vx0 = (ix0 >= 0 && ix0 < IMG_W) ? 1.f : 0.f;
        float vx1 = (ix1 >= 0 && ix1 < IMG_W) ? 1.f : 0.f;
        int ry0 = min(max(iy0, 0), IMG_H - 1) * IMG_W;
        int ry1 = min(max(iy1, 0), IMG_H - 1) * IMG_W;
        int cx0 = min(max(ix0, 0), IMG_W - 1);
        int cx1 = min(max(ix1, 0), IMG_W - 1);
        float wy0 = 1.f - fy, wy1 = fy, wx0 = 1.f - fx, wx1 = fx;
        preW[e] = make_float4(wy0 * wx0 * vy0 * vx0 * m, wy0 * wx1 * vy0 * vx1 * m,
                              wy1 * wx0 * vy1 * vx0 * m, wy1 * wx1 * vy1 * vx1 * m);
        preI[e] = make_int4((ry0 + cx0) * CIN, (ry0 + cx1) * CIN,
                            (ry1 + cx0) * CIN, (ry1 + cx1) * CIN);
    }
    __syncthreads();

    int lane = tid & 63, wave = tid >> 6;   // wave = og: oc [og*32, og*32+32)
    int fr = lane & 15, fq = lane >> 4;
    int chunk = tid & 15, p0 = tid >> 4;    // staging: c-chunk (8c), px base
    int co = ks * 128 + chunk * 8;          // elem offset into this c-half

    // XOR slot layout: slot(s, px) = s*64 + (px ^ s), s in [0,16), px in [0,64)
    auto soff = [](int s, int px) { return (s * 64 + (px ^ s)) * 8; };

    short8 stO[2][4];

    auto stage_loads = [&](int kq) {
#pragma unroll
        for (int it = 0; it < 2; ++it) {
            int px = p0 + it * 32;
            int4 iv = preI[kq * 64 + px];
            stO[it][0] = *(const short8*)&xTb[iv.x + co];
            stO[it][1] = *(const short8*)&xTb[iv.y + co];
            stO[it][2] = *(const short8*)&xTb[iv.z + co];
            stO[it][3] = *(const short8*)&xTb[iv.w + co];
        }
    };
    auto combine_writes = [&](int kq, int bufi) {
#pragma unroll
        for (int it = 0; it < 2; ++it) {
            int px = p0 + it * 32;
            float4 wv = preW[kq * 64 + px];
            short8 o;
#pragma unroll
            for (int j = 0; j < 8; ++j) {
                float v = wv.x * bf2f(stO[it][0][j]) + wv.y * bf2f(stO[it][1][j]) +
                          wv.z * bf2f(stO[it][2][j]) + wv.w * bf2f(stO[it][3][j]);
                o[j] = f2bf(v);
            }
            *(short8*)&Sm[bufi][soff(chunk, px)] = o;
        }
    };

    f32x4 acc[2][4];
#pragma unroll
    for (int m = 0; m < 2; ++m)
#pragma unroll
        for (int n = 0; n < 4; ++n)
            acc[m][n] = (f32x4){0.f, 0.f, 0.f, 0.f};

    stage_loads(0);
    SB;
    combine_writes(0, 0);
    __syncthreads();

#pragma unroll
    for (int kp = 0; kp < 9; ++kp) {
        // [A] aF batch: this kp, this wave's 32 oc x its 128-c half
        short8 aFc[8];
#pragma unroll
        for (int cl = 0; cl < 4; ++cl)
#pragma unroll
            for (int m = 0; m < 2; ++m)
                aFc[cl * 2 + m] = *(const short8*)(wF +
                        (((size_t)((kp * 8 + ks * 4 + cl) * 16 + wave * 2 + m)) * 64 + lane) * 8);
        SB;
        // [B] issue next-kp tap gathers (fly under MFMA)
        if (kp < 8) stage_loads(kp + 1);
        SB;
        // [C] MFMA(kp)
        {
            const short* SmB = Sm[kp & 1];
#pragma unroll
            for (int cl = 0; cl < 4; ++cl)
#pragma unroll
                for (int n = 0; n < 4; ++n) {
                    short8 bF = *(const short8*)&SmB[soff(cl * 4 + fq, n * 16 + fr)];
#pragma unroll
                    for (int m = 0; m < 2; ++m)
                        acc[m][n] = __builtin_amdgcn_mfma_f32_16x16x32_bf16(
                                aFc[cl * 2 + m], bF, acc[m][n], 0, 0, 0);
                }
        }
        SB;
        // [D] combine + ds_write next kp
        if (kp < 8) combine_writes(kp + 1, (kp + 1) & 1);
        __syncthreads();
    }

    // ---- merge the two K-halves: atomicAdd onto zeroed out ----
    float* outb = out + (size_t)b * (OUTC * HWW) + pbase;
#pragma unroll
    for (int m = 0; m < 2; ++m)
#pragma unroll
        for (int n = 0; n < 4; ++n)
#pragma unroll
            for (int r = 0; r < 4; ++r)
                atomicAdd(&outb[(size_t)(wave * 32 + m * 16 + fq * 4 + r) * HWW +
                                n * 16 + fr], acc[m][n][r]);
}

extern "C" void kernel_launch(void* const* d_in, const int* in_sizes, int n_in,
                              void* d_out, int out_size, void* d_ws, size_t ws_size,
                              hipStream_t stream) {
    const float* x     = (const float*)d_in[0];
    const float* w_off = (const float*)d_in[1];
    const float* b_off = (const float*)d_in[2];
    const float* w_dcn = (const float*)d_in[3];
    float* out = (float*)d_out;

    short* xT  = (short*)d_ws;                          // 4*4096*256 bf16 = 8.4 MB
    float* P   = (float*)(xT + (size_t)4 * HWW * CIN);  // 4*32*4096 f32 = 2.1 MB
    short* wF  = (short*)(P + (size_t)4 * 32 * HWW);    // 73728*8 bf16 = 1.18 MB
    short* wFo = wF + (size_t)73728 * 8;                // 9216*8 bf16 = 147 KB

    hipMemsetAsync(out, 0, (size_t)out_size * sizeof(float), stream);
    prep<<<1348, 256, 0, stream>>>(x, w_dcn, w_off, xT, wF, wFo);
    offs_mfma<<<512, 256, 0, stream>>>(xT, wFo, P);
    dcn_main<<<512, 512, 0, stream>>>(xT, b_off, P, wF, out);
}

// Round 10
// 63.255 us; speedup vs baseline: 1.3902x; 1.3902x over previous
//
#include <hip/hip_runtime.h>

typedef __attribute__((ext_vector_type(8))) short short8;
typedef __attribute__((ext_vector_type(4))) float f32x4;

#define CIN 256
#define OUTC 256
#define HWW 4096
#define IMG_H 64
#define IMG_W 64
#define SROW 264   // offs_mfma LDS row stride (256 + 8 pad)
#define SB __builtin_amdgcn_sched_barrier(0)

__device__ __forceinline__ short f2bf(float f) {
    unsigned u = __float_as_uint(f);
    u += 0x7fffu + ((u >> 16) & 1u);
    return (short)(u >> 16);
}
__device__ __forceinline__ float bf2f(short s) {
    return __uint_as_float(((unsigned)(unsigned short)s) << 16);
}

// ---------------- Fused prep: xpose (0..1023), wprep 16-octile layout
//                  (1024..1311), wprep_off (1312..1347) ----------------
__global__ __launch_bounds__(256) void prep(const float* __restrict__ x,
                                            const float* __restrict__ w_dcn,
                                            const float* __restrict__ w_off,
                                            short* __restrict__ xT,
                                            short* __restrict__ wF,
                                            short* __restrict__ wFo) {
    int bid = blockIdx.x;
    if (bid < 1024) {
        __shared__ float T[64][65];
        int p0 = (bid & 63) * 64;
        int c0 = ((bid >> 6) & 3) * 64;
        int b  = bid >> 8;
        int j = threadIdx.x & 63, i = threadIdx.x >> 6;
        const float* xb = x + ((size_t)b * CIN + c0) * HWW + p0;
#pragma unroll
        for (int k = 0; k < 16; ++k) {
            int row = i * 16 + k;
            T[row][j] = xb[(size_t)row * HWW + j];
        }
        __syncthreads();
        short* xTb = xT + ((size_t)b * HWW + p0) * CIN + c0;
#pragma unroll
        for (int k = 0; k < 16; ++k) {
            int prow = i * 16 + k;
            xTb[(size_t)prow * CIN + j] = f2bf(T[j][prow]);
        }
    } else if (bid < 1312) {
        // wF entry g = ((step*16 + octile)*64 + lane); step = kp*8 + chv;
        // oc = octile*16 + (lane&15), c = chv*32 + (lane>>4)*8 + j.
        int g = (bid - 1024) * 256 + threadIdx.x;   // 73728
        int lane = g & 63;
        int rest = g >> 6;
        int octile = rest & 15;
        int step = rest >> 4;
        int kp = step >> 3, chv = step & 7;
        int oc = octile * 16 + (lane & 15);
        int cbase = chv * 32 + (lane >> 4) * 8;
        short8 v;
#pragma unroll
        for (int j = 0; j < 8; ++j)
            v[j] = f2bf(w_dcn[oc * 2304 + (cbase + j) * 9 + kp]);
        *(short8*)(wF + (size_t)g * 8) = v;
    } else {
        int g = (bid - 1312) * 256 + threadIdx.x;   // 9216
        int lane = g & 63;
        int rest = g >> 6;
        int octile = rest & 1;
        int step = rest >> 1;
        int kp = step >> 3, chv = step & 7;
        int oc = octile * 16 + (lane & 15);
        int cbase = chv * 32 + (lane >> 4) * 8;
        short8 v;
#pragma unroll
        for (int j = 0; j < 8; ++j)
            v[j] = (oc < 27) ? f2bf(w_off[(oc * 256 + cbase + j) * 9 + kp]) : (short)0;
        *(short8*)(wFo + (size_t)g * 8) = v;
    }
}

// ---------------- Offset conv: 16x16 MFMA path (unchanged) ----------------
__global__ __launch_bounds__(256) void offs_mfma(
        const short* __restrict__ xT, const short* __restrict__ wFo,
        float* __restrict__ P) {
    __shared__ short Sm[2][32 * SROW];

    int tid = threadIdx.x;
    int d = blockIdx.x;
    int L = (d & 7) * 64 + (d >> 3);
    int b = L >> 7;
    int ph = L & 127;
    int pbase = ph * 32;
    int prow = ph >> 1;
    int pc0 = (ph & 1) * 32;
    const short* xTb = xT + (size_t)b * HWW * CIN;

    int lane = tid & 63, wave = tid >> 6;
    int fr = lane & 15, fq = lane >> 4;
    int octile = wave & 1, pxt = wave >> 1;

    short8 st[4];

    auto loads = [&](int kp) {
        int yy = prow - 1 + kp / 3;
        int dx = kp % 3 - 1;
#pragma unroll
        for (int it = 0; it < 4; ++it) {
            int item = tid + it * 256;
            int cg8 = item & 31, px = item >> 5;
            int xx = pc0 + px + dx;
            bool ok = (yy >= 0 && yy < IMG_H && xx >= 0 && xx < IMG_W);
            int idx = ok ? ((yy * IMG_W + xx) * CIN + cg8 * 8) : 0;
            short8 v = *(const short8*)&xTb[idx];
            if (!ok) v = (short8){0,0,0,0,0,0,0,0};
            st[it] = v;
        }
    };
    auto writes = [&](int bufi) {
#pragma unroll
        for (int it = 0; it < 4; ++it) {
            int item = tid + it * 256;
            int cg8 = item & 31, px = item >> 5;
            *(short8*)&Sm[bufi][px * SROW + cg8 * 8] = st[it];
        }
    };

    f32x4 acc = (f32x4){0.f, 0.f, 0.f, 0.f};

    loads(0); writes(0);
    __syncthreads();
    for (int kp = 0; kp < 9; ++kp) {
        short8 aF[8];
#pragma unroll
        for (int chv = 0; chv < 8; ++chv)
            aF[chv] = *(const short8*)(wFo +
                    (((size_t)((kp * 8 + chv) * 2 + octile)) * 64 + lane) * 8);
        if (kp < 8) loads(kp + 1);
        const short* SmB = Sm[kp & 1];
#pragma unroll
        for (int chv = 0; chv < 8; ++chv) {
            short8 bF = *(const short8*)&SmB[(pxt * 16 + fr) * SROW + chv * 32 + fq * 8];
            acc = __builtin_amdgcn_mfma_f32_16x16x32_bf16(aF[chv], bF, acc, 0, 0, 0);
        }
        if (kp < 8) writes((kp + 1) & 1);
        __syncthreads();
    }

#pragma unroll
    for (int r = 0; r < 4; ++r) {
        int oc = octile * 16 + fq * 4 + r;
        if (oc < 27)
            P[((size_t)b * 32 + oc) * HWW + pbase + pxt * 16 + fr] = acc[r];
    }
}

// ---------------- Main: 64px x 256oc, grid 256 lockstep, pinned pipeline ----
// Sm layout: 16B slot at (s*64 + (px&32) + ((px&31)^s))*8 shorts, s = chunk.
__global__ __launch_bounds__(512, 2) void dcn_main(
        const short* __restrict__ xT, const float* __restrict__ b_off,
        const float* __restrict__ P, const short* __restrict__ wF,
        float* __restrict__ out) {
    __shared__ short Sm[2][32 * 64 * 8];    // 2 x 32 KB
    __shared__ float4 preW[576];            // [kp][px]
    __shared__ int4  preI[576];             // [kp][px] elem offsets (idx*CIN)

    int tid = threadIdx.x;
    int d = blockIdx.x;
    int L = (d & 7) * 32 + (d >> 3);        // XCD swizzle: 256 blocks
    int b = L >> 6;
    int row = L & 63;
    int pbase = row * 64;
    const short* xTb = xT + (size_t)b * HWW * CIN;

    for (int e = tid; e < 576; e += 512) {
        int px = e & 63, kp = e >> 6;
        int p = pbase + px;
        float oy = P[((size_t)b * 32 + 2 * kp) * HWW + p] + b_off[2 * kp];
        float ox = P[((size_t)b * 32 + 2 * kp + 1) * HWW + p] + b_off[2 * kp + 1];
        float ml = P[((size_t)b * 32 + 18 + kp) * HWW + p] + b_off[18 + kp];
        float m = 1.0f / (1.0f + expf(-ml));
        float ys = (float)(row - 1 + kp / 3) + oy;
        float xs = (float)(px - 1 + kp % 3) + ox;
        float y0f = floorf(ys), x0f = floorf(xs);
        float fy = ys - y0f, fx = xs - x0f;
        int iy0 = (int)y0f, ix0 = (int)x0f;
        int iy1 = iy0 + 1, ix1 = ix0 + 1;
        float vy0 = (iy0 >= 0 && iy0 < IMG_H) ? 1.f : 0.f;
        float vy1 = (iy1 >= 0 && iy1 < IMG_H) ? 1.f : 0.f;
        float vx0 = (ix0 >= 0 && ix0 < IMG_W) ? 1.f : 0.f;
        float vx1 = (ix1 >= 0 && ix1 < IMG_W) ? 1.f : 0.f;
        int ry0 = min(max(iy0, 0), IMG_H - 1) * IMG_W;
        int ry1 = min(max(iy1, 0), IMG_H - 1) * IMG_W;
        int cx0 = min(max(ix0, 0), IMG_W - 1);
        int cx1 = min(max(ix1, 0), IMG_W - 1);
        float wy0 = 1.f - fy, wy1 = fy, wx0 = 1.f - fx, wx1 = fx;
        preW[e] = make_float4(wy0 * wx0 * vy0 * vx0 * m, wy0 * wx1 * vy0 * vx1 * m,
                              wy1 * wx0 * vy1 * vx0 * m, wy1 * wx1 * vy1 * vx1 * m);
        preI[e] = make_int4((ry0 + cx0) * CIN, (ry0 + cx1) * CIN,
                            (ry1 + cx0) * CIN, (ry1 + cx1) * CIN);
    }
    __syncthreads();

    int lane = tid & 63, wave = tid >> 6;   // wave = og: oc [og*32, og*32+32)
    int fr = lane & 15, fq = lane >> 4;
    int chunk = tid & 31, p0 = tid >> 5;    // staging coords; px = p0 + it*16
    int co = chunk * 8;

    auto soff = [](int s, int px) { return (s * 64 + (px & 32) + ((px & 31) ^ s)) * 8; };

    short8 stO[4][4];

    auto stage_loads = [&](int kq) {
#pragma unroll
        for (int it = 0; it < 4; ++it) {
            int px = p0 + it * 16;
            int4 iv = preI[kq * 64 + px];
            stO[it][0] = *(const short8*)&xTb[iv.x + co];
            stO[it][1] = *(const short8*)&xTb[iv.y + co];
            stO[it][2] = *(const short8*)&xTb[iv.z + co];
            stO[it][3] = *(const short8*)&xTb[iv.w + co];
        }
    };
    auto combine_writes = [&](int kq, int bufi) {
#pragma unroll
        for (int it = 0; it < 4; ++it) {
            int px = p0 + it * 16;
            float4 wv = preW[kq * 64 + px];
            short8 o;
#pragma unroll
            for (int j = 0; j < 8; ++j) {
                float v = wv.x * bf2f(stO[it][0][j]) + wv.y * bf2f(stO[it][1][j]) +
                          wv.z * bf2f(stO[it][2][j]) + wv.w * bf2f(stO[it][3][j]);
                o[j] = f2bf(v);
            }
            *(short8*)&Sm[bufi][soff(chunk, px)] = o;
        }
    };

    f32x4 acc[2][4];
#pragma unroll
    for (int m = 0; m < 2; ++m)
#pragma unroll
        for (int n = 0; n < 4; ++n)
            acc[m][n] = (f32x4){0.f, 0.f, 0.f, 0.f};

    // prologue
    stage_loads(0);
    SB;
    combine_writes(0, 0);
    __syncthreads();

#pragma unroll
    for (int kp = 0; kp < 9; ++kp) {
        // [A] aF batch for this kp (16 x b128 from L2)
        short8 aFc[16];
#pragma unroll
        for (int chv = 0; chv < 8; ++chv)
#pragma unroll
            for (int m = 0; m < 2; ++m)
                aFc[chv * 2 + m] = *(const short8*)(wF +
                        (((size_t)((kp * 8 + chv) * 16 + wave * 2 + m)) * 64 + lane) * 8);
        SB;
        // [B] issue next-kp tap gathers; they fly during MFMA below
        if (kp < 8) stage_loads(kp + 1);
        SB;
        // pin: all 16 aF loads must be issued & complete HERE (taps stay in flight)
        asm volatile("" ::
            "v"(aFc[0]), "v"(aFc[1]), "v"(aFc[2]), "v"(aFc[3]),
            "v"(aFc[4]), "v"(aFc[5]), "v"(aFc[6]), "v"(aFc[7]),
            "v"(aFc[8]), "v"(aFc[9]), "v"(aFc[10]), "v"(aFc[11]),
            "v"(aFc[12]), "v"(aFc[13]), "v"(aFc[14]), "v"(aFc[15]));
        SB;
        // [C] MFMA(kp)
        {
            const short* SmB = Sm[kp & 1];
#pragma unroll
            for (int chv = 0; chv < 8; ++chv)
#pragma unroll
                for (int n = 0; n < 4; ++n) {
                    short8 bF = *(const short8*)&SmB[soff(chv * 4 + fq, n * 16 + fr)];
#pragma unroll
                    for (int m = 0; m < 2; ++m)
                        acc[m][n] = __builtin_amdgcn_mfma_f32_16x16x32_bf16(
                                aFc[chv * 2 + m], bF, acc[m][n], 0, 0, 0);
                }
        }
        SB;
        // pin taps: all issued at [B], completed by now under the MFMAs
        asm volatile("" ::
            "v"(stO[0][0]), "v"(stO[0][1]), "v"(stO[0][2]), "v"(stO[0][3]),
            "v"(stO[1][0]), "v"(stO[1][1]), "v"(stO[1][2]), "v"(stO[1][3]),
            "v"(stO[2][0]), "v"(stO[2][1]), "v"(stO[2][2]), "v"(stO[2][3]),
            "v"(stO[3][0]), "v"(stO[3][1]), "v"(stO[3][2]), "v"(stO[3][3]));
        SB;
        // [D] combine + ds_write next kp
        if (kp < 8) combine_writes(kp + 1, (kp + 1) & 1);
        __syncthreads();
    }

    float* outb = out + (size_t)b * (OUTC * HWW) + pbase;
#pragma unroll
    for (int m = 0; m < 2; ++m)
#pragma unroll
        for (int n = 0; n < 4; ++n)
#pragma unroll
            for (int r = 0; r < 4; ++r)
                outb[(size_t)(wave * 32 + m * 16 + fq * 4 + r) * HWW + n * 16 + fr] =
                        acc[m][n][r];
}

extern "C" void kernel_launch(void* const* d_in, const int* in_sizes, int n_in,
                              void* d_out, int out_size, void* d_ws, size_t ws_size,
                              hipStream_t stream) {
    const float* x     = (const float*)d_in[0];
    const float* w_off = (const float*)d_in[1];
    const float* b_off = (const float*)d_in[2];
    const float* w_dcn = (const float*)d_in[3];
    float* out = (float*)d_out;

    short* xT  = (short*)d_ws;                          // 4*4096*256 bf16 = 8.4 MB
    float* P   = (float*)(xT + (size_t)4 * HWW * CIN);  // 4*32*4096 f32 = 2.1 MB
    short* wF  = (short*)(P + (size_t)4 * 32 * HWW);    // 73728*8 bf16 = 1.18 MB
    short* wFo = wF + (size_t)73728 * 8;                // 9216*8 bf16 = 147 KB

    prep<<<1348, 256, 0, stream>>>(x, w_dcn, w_off, xT, wF, wFo);
    offs_mfma<<<512, 256, 0, stream>>>(xT, wFo, P);
    dcn_main<<<256, 512, 0, stream>>>(xT, b_off, P, wF, out);
}

// Round 11
// 58.294 us; speedup vs baseline: 1.5085x; 1.0851x over previous
//
#include <hip/hip_runtime.h>

typedef __attribute__((ext_vector_type(8))) short short8;
typedef __attribute__((ext_vector_type(4))) float f32x4;

#define CIN 256
#define OUTC 256
#define HWW 4096
#define IMG_H 64
#define IMG_W 64
#define SROW 264   // offs_mfma LDS row stride (256 + 8 pad)
#define SB __builtin_amdgcn_sched_barrier(0)
#define GLOAD(dst, addr) \
    asm volatile("global_load_dwordx4 %0, %1, off" : "=v"(dst) : "v"(addr) : "memory")
#define WAITVM(n) asm volatile("s_waitcnt vmcnt(" #n ")" ::: "memory")
#define WAITLGKM  asm volatile("s_waitcnt lgkmcnt(0)" ::: "memory")

__device__ __forceinline__ short f2bf(float f) {
    unsigned u = __float_as_uint(f);
    u += 0x7fffu + ((u >> 16) & 1u);
    return (short)(u >> 16);
}
__device__ __forceinline__ float bf2f(short s) {
    return __uint_as_float(((unsigned)(unsigned short)s) << 16);
}

// ---------------- Fused prep: xpose (0..1023), wprep 16-octile layout
//                  (1024..1311), wprep_off (1312..1347) ----------------
__global__ __launch_bounds__(256) void prep(const float* __restrict__ x,
                                            const float* __restrict__ w_dcn,
                                            const float* __restrict__ w_off,
                                            short* __restrict__ xT,
                                            short* __restrict__ wF,
                                            short* __restrict__ wFo) {
    int bid = blockIdx.x;
    if (bid < 1024) {
        __shared__ float T[64][65];
        int p0 = (bid & 63) * 64;
        int c0 = ((bid >> 6) & 3) * 64;
        int b  = bid >> 8;
        int j = threadIdx.x & 63, i = threadIdx.x >> 6;
        const float* xb = x + ((size_t)b * CIN + c0) * HWW + p0;
#pragma unroll
        for (int k = 0; k < 16; ++k) {
            int row = i * 16 + k;
            T[row][j] = xb[(size_t)row * HWW + j];
        }
        __syncthreads();
        short* xTb = xT + ((size_t)b * HWW + p0) * CIN + c0;
#pragma unroll
        for (int k = 0; k < 16; ++k) {
            int prow = i * 16 + k;
            xTb[(size_t)prow * CIN + j] = f2bf(T[j][prow]);
        }
    } else if (bid < 1312) {
        // wF entry g = ((step*16 + octile)*64 + lane); step = kp*8 + chv;
        // oc = octile*16 + (lane&15), c = chv*32 + (lane>>4)*8 + j.
        int g = (bid - 1024) * 256 + threadIdx.x;   // 73728
        int lane = g & 63;
        int rest = g >> 6;
        int octile = rest & 15;
        int step = rest >> 4;
        int kp = step >> 3, chv = step & 7;
        int oc = octile * 16 + (lane & 15);
        int cbase = chv * 32 + (lane >> 4) * 8;
        short8 v;
#pragma unroll
        for (int j = 0; j < 8; ++j)
            v[j] = f2bf(w_dcn[oc * 2304 + (cbase + j) * 9 + kp]);
        *(short8*)(wF + (size_t)g * 8) = v;
    } else {
        int g = (bid - 1312) * 256 + threadIdx.x;   // 9216
        int lane = g & 63;
        int rest = g >> 6;
        int octile = rest & 1;
        int step = rest >> 1;
        int kp = step >> 3, chv = step & 7;
        int oc = octile * 16 + (lane & 15);
        int cbase = chv * 32 + (lane >> 4) * 8;
        short8 v;
#pragma unroll
        for (int j = 0; j < 8; ++j)
            v[j] = (oc < 27) ? f2bf(w_off[(oc * 256 + cbase + j) * 9 + kp]) : (short)0;
        *(short8*)(wFo + (size_t)g * 8) = v;
    }
}

// ---------------- Offset conv: 16x16 MFMA path (unchanged) ----------------
__global__ __launch_bounds__(256) void offs_mfma(
        const short* __restrict__ xT, const short* __restrict__ wFo,
        float* __restrict__ P) {
    __shared__ short Sm[2][32 * SROW];

    int tid = threadIdx.x;
    int d = blockIdx.x;
    int L = (d & 7) * 64 + (d >> 3);
    int b = L >> 7;
    int ph = L & 127;
    int pbase = ph * 32;
    int prow = ph >> 1;
    int pc0 = (ph & 1) * 32;
    const short* xTb = xT + (size_t)b * HWW * CIN;

    int lane = tid & 63, wave = tid >> 6;
    int fr = lane & 15, fq = lane >> 4;
    int octile = wave & 1, pxt = wave >> 1;

    short8 st[4];

    auto loads = [&](int kp) {
        int yy = prow - 1 + kp / 3;
        int dx = kp % 3 - 1;
#pragma unroll
        for (int it = 0; it < 4; ++it) {
            int item = tid + it * 256;
            int cg8 = item & 31, px = item >> 5;
            int xx = pc0 + px + dx;
            bool ok = (yy >= 0 && yy < IMG_H && xx >= 0 && xx < IMG_W);
            int idx = ok ? ((yy * IMG_W + xx) * CIN + cg8 * 8) : 0;
            short8 v = *(const short8*)&xTb[idx];
            if (!ok) v = (short8){0,0,0,0,0,0,0,0};
            st[it] = v;
        }
    };
    auto writes = [&](int bufi) {
#pragma unroll
        for (int it = 0; it < 4; ++it) {
            int item = tid + it * 256;
            int cg8 = item & 31, px = item >> 5;
            *(short8*)&Sm[bufi][px * SROW + cg8 * 8] = st[it];
        }
    };

    f32x4 acc = (f32x4){0.f, 0.f, 0.f, 0.f};

    loads(0); writes(0);
    __syncthreads();
    for (int kp = 0; kp < 9; ++kp) {
        short8 aF[8];
#pragma unroll
        for (int chv = 0; chv < 8; ++chv)
            aF[chv] = *(const short8*)(wFo +
                    (((size_t)((kp * 8 + chv) * 2 + octile)) * 64 + lane) * 8);
        if (kp < 8) loads(kp + 1);
        const short* SmB = Sm[kp & 1];
#pragma unroll
        for (int chv = 0; chv < 8; ++chv) {
            short8 bF = *(const short8*)&SmB[(pxt * 16 + fr) * SROW + chv * 32 + fq * 8];
            acc = __builtin_amdgcn_mfma_f32_16x16x32_bf16(aF[chv], bF, acc, 0, 0, 0);
        }
        if (kp < 8) writes((kp + 1) & 1);
        __syncthreads();
    }

#pragma unroll
    for (int r = 0; r < 4; ++r) {
        int oc = octile * 16 + fq * 4 + r;
        if (oc < 27)
            P[((size_t)b * 32 + oc) * HWW + pbase + pxt * 16 + fr] = acc[r];
    }
}

// ---------------- Main: 64px x 256oc, counted-vmcnt pipeline (T3/T4) --------
// Per kp: issue aF(kp) -> vmcnt(16) [taps(kp) ready] -> combine+ds_write ->
// issue taps(kp+1) -> lgkmcnt(0); raw s_barrier -> vmcnt(16) [aF ready,
// taps(kp+1) stay in flight ACROSS the barrier] -> 64 MFMA.
__global__ __launch_bounds__(512, 2) void dcn_main(
        const short* __restrict__ xT, const float* __restrict__ b_off,
        const float* __restrict__ P, const short* __restrict__ wF,
        float* __restrict__ out) {
    __shared__ short Sm[2][32 * 64 * 8];    // 2 x 32 KB
    __shared__ float4 preW[576];            // [kp][px]
    __shared__ int4  preI[576];             // [kp][px] elem offsets (idx*CIN)

    int tid = threadIdx.x;
    int d = blockIdx.x;
    int L = (d & 7) * 32 + (d >> 3);        // XCD swizzle: 256 blocks
    int b = L >> 6;
    int row = L & 63;
    int pbase = row * 64;
    const short* xTb = xT + (size_t)b * HWW * CIN;

    for (int e = tid; e < 576; e += 512) {
        int px = e & 63, kp = e >> 6;
        int p = pbase + px;
        float oy = P[((size_t)b * 32 + 2 * kp) * HWW + p] + b_off[2 * kp];
        float ox = P[((size_t)b * 32 + 2 * kp + 1) * HWW + p] + b_off[2 * kp + 1];
        float ml = P[((size_t)b * 32 + 18 + kp) * HWW + p] + b_off[18 + kp];
        float m = 1.0f / (1.0f + expf(-ml));
        float ys = (float)(row - 1 + kp / 3) + oy;
        float xs = (float)(px - 1 + kp % 3) + ox;
        float y0f = floorf(ys), x0f = floorf(xs);
        float fy = ys - y0f, fx = xs - x0f;
        int iy0 = (int)y0f, ix0 = (int)x0f;
        int iy1 = iy0 + 1, ix1 = ix0 + 1;
        float vy0 = (iy0 >= 0 && iy0 < IMG_H) ? 1.f : 0.f;
        float vy1 = (iy1 >= 0 && iy1 < IMG_H) ? 1.f : 0.f;
        float vx0 = (ix0 >= 0 && ix0 < IMG_W) ? 1.f : 0.f;
        float vx1 = (ix1 >= 0 && ix1 < IMG_W) ? 1.f : 0.f;
        int ry0 = min(max(iy0, 0), IMG_H - 1) * IMG_W;
        int ry1 = min(max(iy1, 0), IMG_H - 1) * IMG_W;
        int cx0 = min(max(ix0, 0), IMG_W - 1);
        int cx1 = min(max(ix1, 0), IMG_W - 1);
        float wy0 = 1.f - fy, wy1 = fy, wx0 = 1.f - fx, wx1 = fx;
        preW[e] = make_float4(wy0 * wx0 * vy0 * vx0 * m, wy0 * wx1 * vy0 * vx1 * m,
                              wy1 * wx0 * vy1 * vx0 * m, wy1 * wx1 * vy1 * vx1 * m);
        preI[e] = make_int4((ry0 + cx0) * CIN, (ry0 + cx1) * CIN,
                            (ry1 + cx0) * CIN, (ry1 + cx1) * CIN);
    }
    __syncthreads();   // full drain: 0 outstanding VMEM entering the loop

    int lane = tid & 63, wave = tid >> 6;   // wave = og: oc [og*32, og*32+32)
    int fr = lane & 15, fq = lane >> 4;
    int chunk = tid & 31, p0 = tid >> 5;    // staging coords; px = p0 + it*16
    int co = chunk * 8;

    auto soff = [](int s, int px) { return (s * 64 + (px & 32) + ((px & 31) ^ s)) * 8; };

    short8 stO[4][4];
    short8 aFc[16];

    // issue the 16 tap loads for a kp (asm: cannot be sunk or drained implicitly)
    auto issue_taps = [&](int kq) {
#pragma unroll
        for (int it = 0; it < 4; ++it) {
            int px = p0 + it * 16;
            int4 iv = preI[kq * 64 + px];
            GLOAD(stO[it][0], (const short8*)&xTb[iv.x + co]);
            GLOAD(stO[it][1], (const short8*)&xTb[iv.y + co]);
            GLOAD(stO[it][2], (const short8*)&xTb[iv.z + co]);
            GLOAD(stO[it][3], (const short8*)&xTb[iv.w + co]);
        }
    };
    auto combine_writes = [&](int kq, int bufi) {
#pragma unroll
        for (int it = 0; it < 4; ++it) {
            int px = p0 + it * 16;
            float4 wv = preW[kq * 64 + px];
            short8 o;
#pragma unroll
            for (int j = 0; j < 8; ++j) {
                float v = wv.x * bf2f(stO[it][0][j]) + wv.y * bf2f(stO[it][1][j]) +
                          wv.z * bf2f(stO[it][2][j]) + wv.w * bf2f(stO[it][3][j]);
                o[j] = f2bf(v);
            }
            *(short8*)&Sm[bufi][soff(chunk, px)] = o;
        }
    };

    f32x4 acc[2][4];
#pragma unroll
    for (int m = 0; m < 2; ++m)
#pragma unroll
        for (int n = 0; n < 4; ++n)
            acc[m][n] = (f32x4){0.f, 0.f, 0.f, 0.f};

    // prologue: taps(0) in flight
    issue_taps(0);
    SB;

#pragma unroll
    for (int kp = 0; kp < 9; ++kp) {
        const int bufi = kp & 1;
        // [P1] issue aF(kp): 16 asm loads (newest; taps(kp) are older)
#pragma unroll
        for (int chv = 0; chv < 8; ++chv)
#pragma unroll
            for (int m = 0; m < 2; ++m)
                GLOAD(aFc[chv * 2 + m], (const short8*)(wF +
                        (((size_t)((kp * 8 + chv) * 16 + wave * 2 + m)) * 64 + lane) * 8));
        SB;
        // [P2] oldest 16 (taps(kp)) retired; aF(kp) still in flight
        WAITVM(16); SB;
        // [P3] combine(kp) -> Sm[bufi]
        combine_writes(kp, bufi);
        SB;
        // [P3.5] issue taps(kp+1): fly across the barrier and under MFMA
        if (kp < 8) issue_taps(kp + 1);
        SB;
        // [P4] publish Sm[bufi] block-wide (NO vmcnt drain — raw barrier)
        WAITLGKM;
        __builtin_amdgcn_s_barrier();
        SB;
        // [P4.5] aF(kp) retired; taps(kp+1) remain outstanding
        if (kp < 8) { WAITVM(16); } else { WAITVM(0); }
        SB;
        // [P5] MFMA(kp)
        {
            const short* SmB = Sm[bufi];
#pragma unroll
            for (int chv = 0; chv < 8; ++chv)
#pragma unroll
                for (int n = 0; n < 4; ++n) {
                    short8 bF = *(const short8*)&SmB[soff(chv * 4 + fq, n * 16 + fr)];
#pragma unroll
                    for (int m = 0; m < 2; ++m)
                        acc[m][n] = __builtin_amdgcn_mfma_f32_16x16x32_bf16(
                                aFc[chv * 2 + m], bF, acc[m][n], 0, 0, 0);
                }
        }
        SB;
    }

    float* outb = out + (size_t)b * (OUTC * HWW) + pbase;
#pragma unroll
    for (int m = 0; m < 2; ++m)
#pragma unroll
        for (int n = 0; n < 4; ++n)
#pragma unroll
            for (int r = 0; r < 4; ++r)
                outb[(size_t)(wave * 32 + m * 16 + fq * 4 + r) * HWW + n * 16 + fr] =
                        acc[m][n][r];
}

extern "C" void kernel_launch(void* const* d_in, const int* in_sizes, int n_in,
                              void* d_out, int out_size, void* d_ws, size_t ws_size,
                              hipStream_t stream) {
    const float* x     = (const float*)d_in[0];
    const float* w_off = (const float*)d_in[1];
    const float* b_off = (const float*)d_in[2];
    const float* w_dcn = (const float*)d_in[3];
    float* out = (float*)d_out;

    short* xT  = (short*)d_ws;                          // 4*4096*256 bf16 = 8.4 MB
    float* P   = (float*)(xT + (size_t)4 * HWW * CIN);  // 4*32*4096 f32 = 2.1 MB
    short* wF  = (short*)(P + (size_t)4 * 32 * HWW);    // 73728*8 bf16 = 1.18 MB
    short* wFo = wF + (size_t)73728 * 8;                // 9216*8 bf16 = 147 KB

    prep<<<1348, 256, 0, stream>>>(x, w_dcn, w_off, xT, wF, wFo);
    offs_mfma<<<512, 256, 0, stream>>>(xT, wFo, P);
    dcn_main<<<256, 512, 0, stream>>>(xT, b_off, P, wF, out);
}